// Round 14
// baseline (157.298 us; speedup 1.0000x reference)
//
#include <hip/hip_runtime.h>
#include <hip/hip_bf16.h>

#define N_NODES 50000
#define N_EDGES 800000
#define FDIM 64
#define NBUCK 196          // ceil(50000/256) buckets of 256 nodes
#define CAP 4608           // per-bucket edge capacity: mean 4096 + 8 sigma
#define PAD 16             // one counter per 64B line

typedef __attribute__((ext_vector_type(8))) short short8;
typedef __attribute__((ext_vector_type(4))) float f32x4;

// fp32 -> bf16 bits, round-to-nearest-even
__device__ __forceinline__ unsigned f2bf(float f) {
    unsigned u = __float_as_uint(f);
    u += 0x7fffu + ((u >> 16) & 1u);
    return u >> 16;
}
__device__ __forceinline__ float bf2f_lo(unsigned u) { return __uint_as_float(u << 16); }
__device__ __forceinline__ float bf2f_hi(unsigned u) { return __uint_as_float(u & 0xffff0000u); }

// exclusive scan of one value per thread across a 256-thread block
__device__ __forceinline__ int excl_scan_256(int v, int* wtot, int* wincl) {
    const int t = threadIdx.x, lane = t & 63, w = t >> 6;
    int sv = v;
#pragma unroll
    for (int off = 1; off < 64; off <<= 1) {
        int u = __shfl_up(sv, off, 64);
        if (lane >= off) sv += u;
    }
    if (lane == 63) wtot[w] = sv;
    __syncthreads();
    if (w == 0 && lane < 4) {
        int incl = 0;
#pragma unroll
        for (int k = 0; k < 4; ++k)
            if (k <= lane) incl += wtot[k];
        wincl[lane] = incl;
    }
    __syncthreads();
    return (w ? wincl[w - 1] : 0) + sv - v;
}

// ---------------------------------------------------------------------------
// mega-preprocess (fused, all block-families independent):
//   [0,3124]    convert x0 -> bf16
//   [3125,3128] pack weights into MFMA B-fragment order
//   [3129,3910] bucket scatter: rank edges per bucket in LDS, reserve space in
//               the bucket's FIXED region [bk*CAP,...) (cursors pre-zeroed by
//               memset), write packed (dst<<16)|src
// ---------------------------------------------------------------------------
__global__ __launch_bounds__(256)
void preprocess_kernel(const float* __restrict__ x0, unsigned short* __restrict__ x_bf,
                       const float* __restrict__ Wl0, const float* __restrict__ Wr0,
                       const float* __restrict__ Wl1, const float* __restrict__ Wr1,
                       unsigned short* __restrict__ pW,
                       const int* __restrict__ src, const int* __restrict__ dst,
                       int* __restrict__ cur_pad, unsigned* __restrict__ ebuf) {
    const int b = blockIdx.x;
    const int t = threadIdx.x;
    if (b < 3125) {                       // convert: 3125*256*4 = 3.2M exactly
        int i = (b * 256 + t) * 4;
        float4 v = *(const float4*)(x0 + i);
        uint2 o;
        o.x = f2bf(v.x) | (f2bf(v.y) << 16);
        o.y = f2bf(v.z) | (f2bf(v.w) << 16);
        *(uint2*)(x_bf + i) = o;
    } else if (b < 3129) {                // pack W into MFMA B-fragment order
        const float* Wsrc[4] = {Wl0, Wr0, Wl1, Wr1};
        const float* W = Wsrc[b - 3125];
        unsigned short* P = pW + (b - 3125) * FDIM * FDIM;
        for (int idx = t; idx < FDIM * FDIM; idx += 256) {
            int j = idx & 7;
            int lane = (idx >> 3) & 63;
            int g = idx >> 9;             // ct*2 + kk
            int ct = g >> 1, kk = g & 1;
            int k = kk * 32 + ((lane >> 4) & 3) * 8 + j;
            int col = ct * 16 + (lane & 15);
            P[idx] = (unsigned short)f2bf(W[k * FDIM + col]);
        }
    } else {                              // bucket scatter: 782 blocks x 1024 edges
        __shared__ int h[NBUCK];
        __shared__ int base[NBUCK];
        if (t < NBUCK) h[t] = 0;
        __syncthreads();

        int e0 = (b - 3129) * 1024;
        int bk[4], rk[4]; unsigned pk[4];
#pragma unroll
        for (int k = 0; k < 4; ++k) {
            int e = e0 + k * 256 + t;
            if (e < N_EDGES) {
                int d = dst[e];
                bk[k] = d >> 8;
                pk[k] = ((unsigned)d << 16) | (unsigned)src[e];
                rk[k] = atomicAdd(&h[bk[k]], 1);
            } else bk[k] = -1;
        }
        __syncthreads();
        if (t < NBUCK) {
            int c = h[t];
            base[t] = c ? (t * CAP + atomicAdd(&cur_pad[t * PAD], c)) : 0;
        }
        __syncthreads();
#pragma unroll
        for (int k = 0; k < 4; ++k)
            if (bk[k] >= 0) ebuf[base[bk[k]] + rk[k]] = pk[k];
    }
}

// ---------------------------------------------------------------------------
// bucket CSR finalize: one block per bucket (256 nodes). LDS histogram of
// dst&255 -> scan -> row_start (absolute, bucket-padded csr) + deg (u16);
// LDS-cursor scatter of src u16 into the bucket's contiguous window.
// ---------------------------------------------------------------------------
__global__ __launch_bounds__(256)
void bucket_csr_kernel(const unsigned* __restrict__ ebuf, const int* __restrict__ cur_pad,
                       int* __restrict__ row_start, unsigned short* __restrict__ degs,
                       unsigned short* __restrict__ csr) {
    __shared__ int cnt[256];
    __shared__ int cur[256];
    __shared__ int wtot[4], wincl[4];
    const int b = blockIdx.x;
    const int t = threadIdx.x;
    const int s = b * CAP;
    const int e = s + cur_pad[b * PAD];

    cnt[t] = 0;
    __syncthreads();
    for (int i = s + t; i < e; i += 256)
        atomicAdd(&cnt[(ebuf[i] >> 16) & 255], 1);
    __syncthreads();

    int c = cnt[t];
    int ex = excl_scan_256(c, wtot, wincl);
    cur[t] = ex;
    int node = b * 256 + t;
    if (node < N_NODES) {
        row_start[node] = s + ex;
        degs[node] = (unsigned short)c;
    }
    __syncthreads();

    for (int i = s + t; i < e; i += 256) {
        unsigned pk = ebuf[i];
        int pos = s + atomicAdd(&cur[(pk >> 16) & 255], 1);
        csr[pos] = (unsigned short)pk;
    }
}

// ---------------------------------------------------------------------------
// fused SAGE layer, slot-parallel gather. Block = 128 (2 waves), 16 nodes.
// Gather: wave = 8 slots x 8 lanes; slot owns node r = w*8+slot, lane covers
//   col-oct c; walks its own edge list with 8 rows in flight (64/wave);
//   NO cross-lane reduction. mean+self staged in LDS bf16, octs XOR-swizzled
//   by row&7. MFMA: wave w does col-tiles 2w,2w+1.
//   A[m=lane&15][k=(lane>>4)*8+j]; C/D: col=lane&15, row=(lane>>4)*4+reg.
// Grid 3125 (x16 = 50000 exactly).
// ---------------------------------------------------------------------------
template <bool OUT_BF16>
__global__ __launch_bounds__(128)
void sage_fused_kernel(const unsigned short* __restrict__ xb,
                       const int* __restrict__ row_start,
                       const unsigned short* __restrict__ degs,
                       const unsigned short* __restrict__ csr,
                       const unsigned short* __restrict__ pWl,
                       const float* __restrict__ bl,
                       const unsigned short* __restrict__ pWr,
                       float* __restrict__ out_f32,
                       unsigned short* __restrict__ out_bf) {
    __shared__ __align__(16) unsigned short smean[16][FDIM];
    __shared__ __align__(16) unsigned short sxs[16][FDIM];

    const int w = threadIdx.x >> 6;       // 0..1
    const int lane = threadIdx.x & 63;
    const int slot = lane >> 3;           // 0..7 -> node within wave
    const int c = lane & 7;               // col-oct 0..7
    const int base = blockIdx.x * 16;
    const int r = w * 8 + slot;           // local row 0..15
    const int n = base + r;

    const int rs = row_start[n];
    const int deg = degs[n];
    const int po = (c ^ (r & 7)) * 8;     // swizzled physical oct offset

    // self row: stage to LDS + seed accumulator
    uint4 sv = *(const uint4*)(xb + (size_t)n * FDIM + c * 8);
    *(uint4*)(&sxs[r][po]) = sv;
    float s0 = bf2f_lo(sv.x), s1 = bf2f_hi(sv.x);
    float s2 = bf2f_lo(sv.y), s3 = bf2f_hi(sv.y);
    float s4 = bf2f_lo(sv.z), s5 = bf2f_hi(sv.z);
    float s6 = bf2f_lo(sv.w), s7 = bf2f_hi(sv.w);

#define ACC(v_) do {                                   \
        s0 += bf2f_lo(v_.x); s1 += bf2f_hi(v_.x);      \
        s2 += bf2f_lo(v_.y); s3 += bf2f_hi(v_.y);      \
        s4 += bf2f_lo(v_.z); s5 += bf2f_hi(v_.z);      \
        s6 += bf2f_lo(v_.w); s7 += bf2f_hi(v_.w);      \
    } while (0)

    int idx = rs;
    int rem = deg;
    while (rem >= 8) {                    // 8 rows in flight per slot
        int a0 = csr[idx + 0];
        int a1 = csr[idx + 1];
        int a2 = csr[idx + 2];
        int a3 = csr[idx + 3];
        int a4 = csr[idx + 4];
        int a5 = csr[idx + 5];
        int a6 = csr[idx + 6];
        int a7 = csr[idx + 7];
        uint4 v0 = *(const uint4*)(xb + (size_t)a0 * FDIM + c * 8);
        uint4 v1 = *(const uint4*)(xb + (size_t)a1 * FDIM + c * 8);
        uint4 v2 = *(const uint4*)(xb + (size_t)a2 * FDIM + c * 8);
        uint4 v3 = *(const uint4*)(xb + (size_t)a3 * FDIM + c * 8);
        uint4 v4 = *(const uint4*)(xb + (size_t)a4 * FDIM + c * 8);
        uint4 v5 = *(const uint4*)(xb + (size_t)a5 * FDIM + c * 8);
        uint4 v6 = *(const uint4*)(xb + (size_t)a6 * FDIM + c * 8);
        uint4 v7 = *(const uint4*)(xb + (size_t)a7 * FDIM + c * 8);
        ACC(v0); ACC(v1); ACC(v2); ACC(v3);
        ACC(v4); ACC(v5); ACC(v6); ACC(v7);
        idx += 8; rem -= 8;
    }
    if (rem >= 4) {
        int a0 = csr[idx + 0];
        int a1 = csr[idx + 1];
        int a2 = csr[idx + 2];
        int a3 = csr[idx + 3];
        uint4 v0 = *(const uint4*)(xb + (size_t)a0 * FDIM + c * 8);
        uint4 v1 = *(const uint4*)(xb + (size_t)a1 * FDIM + c * 8);
        uint4 v2 = *(const uint4*)(xb + (size_t)a2 * FDIM + c * 8);
        uint4 v3 = *(const uint4*)(xb + (size_t)a3 * FDIM + c * 8);
        ACC(v0); ACC(v1); ACC(v2); ACC(v3);
        idx += 4; rem -= 4;
    }
    while (rem > 0) {
        int a0 = csr[idx];
        uint4 v0 = *(const uint4*)(xb + (size_t)a0 * FDIM + c * 8);
        ACC(v0);
        ++idx; --rem;
    }
#undef ACC

    const float inv = 1.0f / (float)(deg + 1);
    uint4 o;
    o.x = f2bf(s0 * inv) | (f2bf(s1 * inv) << 16);
    o.y = f2bf(s2 * inv) | (f2bf(s3 * inv) << 16);
    o.z = f2bf(s4 * inv) | (f2bf(s5 * inv) << 16);
    o.w = f2bf(s6 * inv) | (f2bf(s7 * inv) << 16);
    *(uint4*)(&smean[r][po]) = o;
    __syncthreads();

    // ---- MFMA phase: wave w -> col-tiles 2w, 2w+1 ----
    const int qq = lane >> 4;
    const int rr = lane & 15;

    short8 am0 = *(const short8*)(&smean[rr][((0 + qq) ^ (rr & 7)) * 8]);
    short8 am1 = *(const short8*)(&smean[rr][((4 + qq) ^ (rr & 7)) * 8]);
    short8 ax0 = *(const short8*)(&sxs[rr][((0 + qq) ^ (rr & 7)) * 8]);
    short8 ax1 = *(const short8*)(&sxs[rr][((4 + qq) ^ (rr & 7)) * 8]);

    const short8* pl = (const short8*)pWl;
    const short8* pr = (const short8*)pWr;

#pragma unroll
    for (int tk = 0; tk < 2; ++tk) {
        const int ct = w * 2 + tk;
        short8 bl0v = pl[(ct * 2 + 0) * 64 + lane];
        short8 bl1v = pl[(ct * 2 + 1) * 64 + lane];
        short8 br0v = pr[(ct * 2 + 0) * 64 + lane];
        short8 br1v = pr[(ct * 2 + 1) * 64 + lane];

        float b = bl[ct * 16 + rr];
        f32x4 acc = {b, b, b, b};
        acc = __builtin_amdgcn_mfma_f32_16x16x32_bf16(am0, bl0v, acc, 0, 0, 0);
        acc = __builtin_amdgcn_mfma_f32_16x16x32_bf16(am1, bl1v, acc, 0, 0, 0);
        acc = __builtin_amdgcn_mfma_f32_16x16x32_bf16(ax0, br0v, acc, 0, 0, 0);
        acc = __builtin_amdgcn_mfma_f32_16x16x32_bf16(ax1, br1v, acc, 0, 0, 0);

#pragma unroll
        for (int reg = 0; reg < 4; ++reg) {
            int node = base + qq * 4 + reg;
            float v = fmaxf(acc[reg], 0.0f);
            if (OUT_BF16) out_bf[(size_t)node * FDIM + ct * 16 + rr] = (unsigned short)f2bf(v);
            else          out_f32[(size_t)node * FDIM + ct * 16 + rr] = v;
        }
    }
}

// ---------------------------------------------------------------------------
extern "C" void kernel_launch(void* const* d_in, const int* in_sizes, int n_in,
                              void* d_out, int out_size, void* d_ws, size_t ws_size,
                              hipStream_t stream) {
    const float* x0  = (const float*)d_in[0];
    const int*   ei  = (const int*)d_in[1];
    const float* Wl0 = (const float*)d_in[2];
    const float* bl0 = (const float*)d_in[3];
    const float* Wr0 = (const float*)d_in[4];
    const float* Wl1 = (const float*)d_in[5];
    const float* bl1 = (const float*)d_in[6];
    const float* Wr1 = (const float*)d_in[7];
    float* out = (float*)d_out;

    const int* src = ei;            // edge_index[0]
    const int* dst = ei + N_EDGES;  // edge_index[1]

    // workspace layout (all segments 16B-aligned by construction):
    // cur_pad[3136] | row_start[50000] | degs u16[50000] | ebuf[196*4608] |
    // csr u16[196*4608] | x_bf | h_bf | pW(4x4096)
    int* cur_pad    = (int*)d_ws;                        // 3136 ints
    int* row_start  = cur_pad + 3136;                    // 50000 ints
    unsigned short* degs = (unsigned short*)(row_start + 50000);   // 50000
    unsigned* ebuf  = (unsigned*)(degs + 50000);         // 903168 uints
    unsigned short* csr_u16 = (unsigned short*)(ebuf + NBUCK * CAP);  // 903168
    unsigned short* x_bf = csr_u16 + NBUCK * CAP;
    unsigned short* h_bf = x_bf + (size_t)N_NODES * FDIM;
    unsigned short* pW   = h_bf + (size_t)N_NODES * FDIM;   // 4 x 4096

    hipMemsetAsync(cur_pad, 0, 3136 * sizeof(int), stream);
    preprocess_kernel<<<3911, 256, 0, stream>>>(x0, x_bf, Wl0, Wr0, Wl1, Wr1,
                                                pW, src, dst, cur_pad, ebuf);
    bucket_csr_kernel<<<NBUCK, 256, 0, stream>>>(ebuf, cur_pad, row_start, degs, csr_u16);

    // ---- layer 0 (bf16 out) ----
    sage_fused_kernel<true><<<N_NODES / 16, 128, 0, stream>>>(
        x_bf, row_start, degs, csr_u16, pW + 0 * FDIM * FDIM, bl0,
        pW + 1 * FDIM * FDIM, nullptr, h_bf);
    // ---- layer 1 (fp32 out) ----
    sage_fused_kernel<false><<<N_NODES / 16, 128, 0, stream>>>(
        h_bf, row_start, degs, csr_u16, pW + 2 * FDIM * FDIM, bl1,
        pW + 3 * FDIM * FDIM, out, nullptr);
}

// Round 16
// 155.907 us; speedup vs baseline: 1.0089x; 1.0089x over previous
//
#include <hip/hip_runtime.h>
#include <hip/hip_bf16.h>

#define N_NODES 50000
#define N_EDGES 800000
#define FDIM 64
#define NBUCK 196          // ceil(50000/256) buckets of 256 nodes
#define CAP 4608           // per-bucket ebuf capacity: mean 4096 + 8 sigma
#define CAP2 5632          // per-bucket csr capacity (8-aligned rows: mean ~4996 + 9 sigma)
#define PAD 16             // one counter per 64B line

typedef __attribute__((ext_vector_type(8))) short short8;
typedef __attribute__((ext_vector_type(4))) float f32x4;

// fp32 -> bf16 bits, round-to-nearest-even
__device__ __forceinline__ unsigned f2bf(float f) {
    unsigned u = __float_as_uint(f);
    u += 0x7fffu + ((u >> 16) & 1u);
    return u >> 16;
}
__device__ __forceinline__ float bf2f_lo(unsigned u) { return __uint_as_float(u << 16); }
__device__ __forceinline__ float bf2f_hi(unsigned u) { return __uint_as_float(u & 0xffff0000u); }

// exclusive scan of one value per thread across a 256-thread block
__device__ __forceinline__ int excl_scan_256(int v, int* wtot, int* wincl) {
    const int t = threadIdx.x, lane = t & 63, w = t >> 6;
    int sv = v;
#pragma unroll
    for (int off = 1; off < 64; off <<= 1) {
        int u = __shfl_up(sv, off, 64);
        if (lane >= off) sv += u;
    }
    if (lane == 63) wtot[w] = sv;
    __syncthreads();
    if (w == 0 && lane < 4) {
        int incl = 0;
#pragma unroll
        for (int k = 0; k < 4; ++k)
            if (k <= lane) incl += wtot[k];
        wincl[lane] = incl;
    }
    __syncthreads();
    return (w ? wincl[w - 1] : 0) + sv - v;
}

// ---------------------------------------------------------------------------
// mega-preprocess (fused, all block-families independent):
//   [0,3124]    convert x0 -> bf16
//   [3125,3128] pack weights into MFMA B-fragment order
//   [3129,3910] bucket scatter into fixed regions [bk*CAP,...) of ebuf
// ---------------------------------------------------------------------------
__global__ __launch_bounds__(256)
void preprocess_kernel(const float* __restrict__ x0, unsigned short* __restrict__ x_bf,
                       const float* __restrict__ Wl0, const float* __restrict__ Wr0,
                       const float* __restrict__ Wl1, const float* __restrict__ Wr1,
                       unsigned short* __restrict__ pW,
                       const int* __restrict__ src, const int* __restrict__ dst,
                       int* __restrict__ cur_pad, unsigned* __restrict__ ebuf) {
    const int b = blockIdx.x;
    const int t = threadIdx.x;
    if (b < 3125) {                       // convert: 3125*256*4 = 3.2M exactly
        int i = (b * 256 + t) * 4;
        float4 v = *(const float4*)(x0 + i);
        uint2 o;
        o.x = f2bf(v.x) | (f2bf(v.y) << 16);
        o.y = f2bf(v.z) | (f2bf(v.w) << 16);
        *(uint2*)(x_bf + i) = o;
    } else if (b < 3129) {                // pack W into MFMA B-fragment order
        const float* Wsrc[4] = {Wl0, Wr0, Wl1, Wr1};
        const float* W = Wsrc[b - 3125];
        unsigned short* P = pW + (b - 3125) * FDIM * FDIM;
        for (int idx = t; idx < FDIM * FDIM; idx += 256) {
            int j = idx & 7;
            int lane = (idx >> 3) & 63;
            int g = idx >> 9;             // ct*2 + kk
            int ct = g >> 1, kk = g & 1;
            int k = kk * 32 + ((lane >> 4) & 3) * 8 + j;
            int col = ct * 16 + (lane & 15);
            P[idx] = (unsigned short)f2bf(W[k * FDIM + col]);
        }
    } else {                              // bucket scatter: 782 blocks x 1024 edges
        __shared__ int h[NBUCK];
        __shared__ int base[NBUCK];
        if (t < NBUCK) h[t] = 0;
        __syncthreads();

        int e0 = (b - 3129) * 1024;
        int bk[4], rk[4]; unsigned pk[4];
#pragma unroll
        for (int k = 0; k < 4; ++k) {
            int e = e0 + k * 256 + t;
            if (e < N_EDGES) {
                int d = dst[e];
                bk[k] = d >> 8;
                pk[k] = ((unsigned)d << 16) | (unsigned)src[e];
                rk[k] = atomicAdd(&h[bk[k]], 1);
            } else bk[k] = -1;
        }
        __syncthreads();
        if (t < NBUCK) {
            int c = h[t];
            base[t] = c ? (t * CAP + atomicAdd(&cur_pad[t * PAD], c)) : 0;
        }
        __syncthreads();
#pragma unroll
        for (int k = 0; k < 4; ++k)
            if (bk[k] >= 0) ebuf[base[bk[k]] + rk[k]] = pk[k];
    }
}

// ---------------------------------------------------------------------------
// bucket CSR finalize: one block per bucket (256 nodes). LDS histogram of
// dst&255 -> 8-ALIGNED exclusive scan (each node's csr segment starts at a
// multiple of 8 -> gather can use 16B-aligned uint4 index loads) -> row_start
// (absolute into CAP2-padded csr) + deg; LDS-cursor scatter of src u16.
// ---------------------------------------------------------------------------
__global__ __launch_bounds__(256)
void bucket_csr_kernel(const unsigned* __restrict__ ebuf, const int* __restrict__ cur_pad,
                       int* __restrict__ row_start, unsigned short* __restrict__ degs,
                       unsigned short* __restrict__ csr) {
    __shared__ int cnt[256];
    __shared__ int cur[256];
    __shared__ int wtot[4], wincl[4];
    const int b = blockIdx.x;
    const int t = threadIdx.x;
    const int s = b * CAP;                // ebuf window
    const int e = s + cur_pad[b * PAD];
    const int s2 = b * CAP2;              // csr window (8-aligned rows)

    cnt[t] = 0;
    __syncthreads();
    for (int i = s + t; i < e; i += 256)
        atomicAdd(&cnt[(ebuf[i] >> 16) & 255], 1);
    __syncthreads();

    int c = cnt[t];
    int c8 = (c + 7) & ~7;                // 8-aligned segment size
    int ex = excl_scan_256(c8, wtot, wincl);
    cur[t] = ex;
    int node = b * 256 + t;
    if (node < N_NODES) {
        row_start[node] = s2 + ex;
        degs[node] = (unsigned short)c;
    }
    __syncthreads();

    for (int i = s + t; i < e; i += 256) {
        unsigned pk = ebuf[i];
        int pos = s2 + atomicAdd(&cur[(pk >> 16) & 255], 1);
        csr[pos] = (unsigned short)pk;
    }
}

// ---------------------------------------------------------------------------
// fused SAGE layer, slot-parallel gather with batched index loads.
// Block = 128 (2 waves), 16 nodes. Wave = 8 slots x 8 lanes; slot owns node
// r = w*8+slot; lane covers col-oct c. Indices come 8-at-a-time via one
// 16B-aligned uint4 load (slot-uniform address -> HW broadcast); 8 row loads
// in flight per slot. mean+self staged in LDS bf16, octs XOR-swizzled by
// row&7. MFMA: wave w does col-tiles 2w,2w+1.
// A[m=lane&15][k=(lane>>4)*8+j]; C/D: col=lane&15, row=(lane>>4)*4+reg.
// Grid 3125 (x16 = 50000 exactly).
// ---------------------------------------------------------------------------
template <bool OUT_BF16>
__global__ __launch_bounds__(128)
void sage_fused_kernel(const unsigned short* __restrict__ xb,
                       const int* __restrict__ row_start,
                       const unsigned short* __restrict__ degs,
                       const unsigned short* __restrict__ csr,
                       const unsigned short* __restrict__ pWl,
                       const float* __restrict__ bl,
                       const unsigned short* __restrict__ pWr,
                       float* __restrict__ out_f32,
                       unsigned short* __restrict__ out_bf) {
    __shared__ __align__(16) unsigned short smean[16][FDIM];
    __shared__ __align__(16) unsigned short sxs[16][FDIM];

    const int w = threadIdx.x >> 6;       // 0..1
    const int lane = threadIdx.x & 63;
    const int slot = lane >> 3;           // 0..7 -> node within wave
    const int c = lane & 7;               // col-oct 0..7
    const int base = blockIdx.x * 16;
    const int r = w * 8 + slot;           // local row 0..15
    const int n = base + r;

    // self row first (issues earliest)
    uint4 sv = *(const uint4*)(xb + (size_t)n * FDIM + c * 8);

    const int rs = row_start[n];
    const int deg = degs[n];
    const int po = (c ^ (r & 7)) * 8;     // swizzled physical oct offset

    *(uint4*)(&sxs[r][po]) = sv;
    float s0 = bf2f_lo(sv.x), s1 = bf2f_hi(sv.x);
    float s2 = bf2f_lo(sv.y), s3 = bf2f_hi(sv.y);
    float s4 = bf2f_lo(sv.z), s5 = bf2f_hi(sv.z);
    float s6 = bf2f_lo(sv.w), s7 = bf2f_hi(sv.w);

#define ACC(v_) do {                                   \
        s0 += bf2f_lo(v_.x); s1 += bf2f_hi(v_.x);      \
        s2 += bf2f_lo(v_.y); s3 += bf2f_hi(v_.y);      \
        s4 += bf2f_lo(v_.z); s5 += bf2f_hi(v_.z);      \
        s6 += bf2f_lo(v_.w); s7 += bf2f_hi(v_.w);      \
    } while (0)

    int idx = rs;                         // 8-aligned by construction
    int rem = deg;
    while (rem >= 8) {                    // one uint4 = 8 indices; 8 rows in flight
        uint4 iA = *(const uint4*)(csr + idx);
        int a0 = iA.x & 0xffff, a1 = iA.x >> 16;
        int a2 = iA.y & 0xffff, a3 = iA.y >> 16;
        int a4 = iA.z & 0xffff, a5 = iA.z >> 16;
        int a6 = iA.w & 0xffff, a7 = iA.w >> 16;
        uint4 v0 = *(const uint4*)(xb + (size_t)a0 * FDIM + c * 8);
        uint4 v1 = *(const uint4*)(xb + (size_t)a1 * FDIM + c * 8);
        uint4 v2 = *(const uint4*)(xb + (size_t)a2 * FDIM + c * 8);
        uint4 v3 = *(const uint4*)(xb + (size_t)a3 * FDIM + c * 8);
        uint4 v4 = *(const uint4*)(xb + (size_t)a4 * FDIM + c * 8);
        uint4 v5 = *(const uint4*)(xb + (size_t)a5 * FDIM + c * 8);
        uint4 v6 = *(const uint4*)(xb + (size_t)a6 * FDIM + c * 8);
        uint4 v7 = *(const uint4*)(xb + (size_t)a7 * FDIM + c * 8);
        ACC(v0); ACC(v1); ACC(v2); ACC(v3);
        ACC(v4); ACC(v5); ACC(v6); ACC(v7);
        idx += 8; rem -= 8;
    }
    if (rem > 0) {                        // tail: segment padded to 8, load is safe
        uint4 iA = *(const uint4*)(csr + idx);
        int a[8];
        a[0] = iA.x & 0xffff; a[1] = iA.x >> 16;
        a[2] = iA.y & 0xffff; a[3] = iA.y >> 16;
        a[4] = iA.z & 0xffff; a[5] = iA.z >> 16;
        a[6] = iA.w & 0xffff; a[7] = iA.w >> 16;
#pragma unroll
        for (int k = 0; k < 8; ++k) {
            if (k < rem) {
                uint4 v = *(const uint4*)(xb + (size_t)a[k] * FDIM + c * 8);
                ACC(v);
            }
        }
    }
#undef ACC

    const float inv = 1.0f / (float)(deg + 1);
    uint4 o;
    o.x = f2bf(s0 * inv) | (f2bf(s1 * inv) << 16);
    o.y = f2bf(s2 * inv) | (f2bf(s3 * inv) << 16);
    o.z = f2bf(s4 * inv) | (f2bf(s5 * inv) << 16);
    o.w = f2bf(s6 * inv) | (f2bf(s7 * inv) << 16);
    *(uint4*)(&smean[r][po]) = o;
    __syncthreads();

    // ---- MFMA phase: wave w -> col-tiles 2w, 2w+1 ----
    const int qq = lane >> 4;
    const int rr = lane & 15;

    short8 am0 = *(const short8*)(&smean[rr][((0 + qq) ^ (rr & 7)) * 8]);
    short8 am1 = *(const short8*)(&smean[rr][((4 + qq) ^ (rr & 7)) * 8]);
    short8 ax0 = *(const short8*)(&sxs[rr][((0 + qq) ^ (rr & 7)) * 8]);
    short8 ax1 = *(const short8*)(&sxs[rr][((4 + qq) ^ (rr & 7)) * 8]);

    const short8* pl = (const short8*)pWl;
    const short8* pr = (const short8*)pWr;

#pragma unroll
    for (int tk = 0; tk < 2; ++tk) {
        const int ct = w * 2 + tk;
        short8 bl0v = pl[(ct * 2 + 0) * 64 + lane];
        short8 bl1v = pl[(ct * 2 + 1) * 64 + lane];
        short8 br0v = pr[(ct * 2 + 0) * 64 + lane];
        short8 br1v = pr[(ct * 2 + 1) * 64 + lane];

        float b = bl[ct * 16 + rr];
        f32x4 acc = {b, b, b, b};
        acc = __builtin_amdgcn_mfma_f32_16x16x32_bf16(am0, bl0v, acc, 0, 0, 0);
        acc = __builtin_amdgcn_mfma_f32_16x16x32_bf16(am1, bl1v, acc, 0, 0, 0);
        acc = __builtin_amdgcn_mfma_f32_16x16x32_bf16(ax0, br0v, acc, 0, 0, 0);
        acc = __builtin_amdgcn_mfma_f32_16x16x32_bf16(ax1, br1v, acc, 0, 0, 0);

#pragma unroll
        for (int reg = 0; reg < 4; ++reg) {
            int node = base + qq * 4 + reg;
            float v = fmaxf(acc[reg], 0.0f);
            if (OUT_BF16) out_bf[(size_t)node * FDIM + ct * 16 + rr] = (unsigned short)f2bf(v);
            else          out_f32[(size_t)node * FDIM + ct * 16 + rr] = v;
        }
    }
}

// ---------------------------------------------------------------------------
extern "C" void kernel_launch(void* const* d_in, const int* in_sizes, int n_in,
                              void* d_out, int out_size, void* d_ws, size_t ws_size,
                              hipStream_t stream) {
    const float* x0  = (const float*)d_in[0];
    const int*   ei  = (const int*)d_in[1];
    const float* Wl0 = (const float*)d_in[2];
    const float* bl0 = (const float*)d_in[3];
    const float* Wr0 = (const float*)d_in[4];
    const float* Wl1 = (const float*)d_in[5];
    const float* bl1 = (const float*)d_in[6];
    const float* Wr1 = (const float*)d_in[7];
    float* out = (float*)d_out;

    const int* src = ei;            // edge_index[0]
    const int* dst = ei + N_EDGES;  // edge_index[1]

    // workspace layout (all segments 16B-aligned by construction):
    // cur_pad[3136] | row_start[50000] | degs u16[50000] | ebuf[196*4608] |
    // csr u16[196*5632 + 1024 slack] | x_bf | h_bf | pW(4x4096)
    int* cur_pad    = (int*)d_ws;                        // 3136 ints
    int* row_start  = cur_pad + 3136;                    // 50000 ints
    unsigned short* degs = (unsigned short*)(row_start + 50000);   // 50000
    unsigned* ebuf  = (unsigned*)(degs + 50000);         // 903168 uints
    unsigned short* csr_u16 = (unsigned short*)(ebuf + NBUCK * CAP);
    unsigned short* x_bf = csr_u16 + (NBUCK * CAP2 + 1024);
    unsigned short* h_bf = x_bf + (size_t)N_NODES * FDIM;
    unsigned short* pW   = h_bf + (size_t)N_NODES * FDIM;   // 4 x 4096

    hipMemsetAsync(cur_pad, 0, 3136 * sizeof(int), stream);
    preprocess_kernel<<<3911, 256, 0, stream>>>(x0, x_bf, Wl0, Wr0, Wl1, Wr1,
                                                pW, src, dst, cur_pad, ebuf);
    bucket_csr_kernel<<<NBUCK, 256, 0, stream>>>(ebuf, cur_pad, row_start, degs, csr_u16);

    // ---- layer 0 (bf16 out) ----
    sage_fused_kernel<true><<<N_NODES / 16, 128, 0, stream>>>(
        x_bf, row_start, degs, csr_u16, pW + 0 * FDIM * FDIM, bl0,
        pW + 1 * FDIM * FDIM, nullptr, h_bf);
    // ---- layer 1 (fp32 out) ----
    sage_fused_kernel<false><<<N_NODES / 16, 128, 0, stream>>>(
        h_bf, row_start, degs, csr_u16, pW + 2 * FDIM * FDIM, bl1,
        pW + 3 * FDIM * FDIM, out, nullptr);
}